// Round 9
// baseline (696.563 us; speedup 1.0000x reference)
//
#include <hip/hip_runtime.h>
#include <math.h>

namespace {
constexpr int Bn    = 64;
constexpr int CIN   = 320;
constexpr int COUT  = 640;
constexpr int CIN_G = 32;   // 320/10
constexpr int COUT_G= 64;   // 640/10
constexpr int NH    = 4;
constexpr int Dd    = 160;
constexpr int ALLOCC= 16;
constexpr int Ss    = 1024; // 32*32
constexpr float ATT_SCALE = 0.0395284707521047f; // 640^-0.5

typedef float  f32x4  __attribute__((ext_vector_type(4)));
typedef int    i32x4  __attribute__((ext_vector_type(4)));

__device__ inline unsigned bf16rne(float f) {
    unsigned u = __float_as_uint(f);
    return (u + 0x7FFFu + ((u >> 16) & 1u)) >> 16;
}
__device__ inline unsigned packbf16(float a, float b) {
    return bf16rne(a) | (bf16rne(b) << 16);
}
}

// ---------------- K1: grouped conv3x3 via MFMA implicit GEMM (R4 asm, proven)
__global__ __launch_bounds__(512, 2) void conv_mfma_k(
    const float* __restrict__ x, const float* __restrict__ w1,
    const float* __restrict__ b1, float* __restrict__ out,
    double* __restrict__ statS, double* __restrict__ statS2) {
    __shared__ __align__(16) unsigned short xl[34 * 34 * 32];
    __shared__ __align__(16) unsigned short wl[9 * 64 * 32];

    int bg = blockIdx.x;
    int b = bg / 10, g = bg % 10;
    int tid = threadIdx.x;
    int wid = tid >> 6;
    int lane = tid & 63;
    int lc = lane & 15;
    int kl = (lane >> 4) * 8;

    unsigned* xl32 = (unsigned*)xl;
    unsigned* wl32 = (unsigned*)wl;

    for (int e = tid; e < 34 * 34 * 32 / 8; e += 512)
        *(i32x4*)&xl[e * 8] = i32x4{0, 0, 0, 0};
    __syncthreads();

    const float* xg = x + ((size_t)b * CIN + g * CIN_G) * Ss;
    for (int e = tid; e < 16 * Ss; e += 512) {
        int icp = e & 15, sp = e >> 4;
        int r = (sp >> 5) + 1, c = (sp & 31) + 1;
        float f0 = xg[(size_t)(2 * icp) * Ss + sp];
        float f1 = xg[(size_t)(2 * icp + 1) * Ss + sp];
        xl32[(r * 34 + c) * 16 + icp] = packbf16(f0, f1);
    }
    const float* wg = w1 + (size_t)(g * COUT_G) * (CIN_G * 9);
    for (int e = tid; e < 9 * 64 * 16; e += 512) {
        int icp = e & 15, oc = (e >> 4) & 63, dyx = e >> 10;
        float f0 = wg[oc * 288 + (2 * icp) * 9 + dyx];
        float f1 = wg[oc * 288 + (2 * icp + 1) * 9 + dyx];
        wl32[(dyx * 64 + oc) * 16 + icp] = packbf16(f0, f1);
    }
    __syncthreads();

    f32x4 acc[4][8];
    #pragma unroll
    for (int mt = 0; mt < 4; ++mt)
        #pragma unroll
        for (int nt = 0; nt < 8; ++nt) acc[mt][nt] = f32x4{0.f, 0.f, 0.f, 0.f};

    for (int dyx = 0; dyx < 9; ++dyx) {
        int dy = dyx / 3, dx = dyx % 3;
        const unsigned short* wbase = wl + dyx * 2048 + lc * 32 + kl;
        i32x4 af[4];
        #pragma unroll
        for (int mt = 0; mt < 4; ++mt)
            af[mt] = *(const i32x4*)(wbase + mt * 512);

        const unsigned short* xbase = xl + (dy * 34 + dx + lc) * 32 + kl
                                         + wid * 4 * 1088;
        #pragma unroll
        for (int nt = 0; nt < 8; ++nt) {
            i32x4 bf = *(const i32x4*)(xbase + (nt >> 1) * 1088 + (nt & 1) * 512);
            #pragma unroll
            for (int mt = 0; mt < 4; ++mt)
                asm("v_mfma_f32_16x16x32_bf16 %0, %1, %2, %0"
                    : "+v"(acc[mt][nt]) : "v"(af[mt]), "v"(bf));
        }
    }

    #pragma unroll
    for (int mt = 0; mt < 4; ++mt) {
        #pragma unroll
        for (int r = 0; r < 4; ++r) {
            int ocg = mt * 16 + (lane >> 4) * 4 + r;
            float bias = b1[g * COUT_G + ocg];
            float ps = 0.f, ps2 = 0.f;
            float* orow = out + ((size_t)b * COUT + g * COUT_G + ocg) * Ss
                              + wid * 128 + lc;
            #pragma unroll
            for (int nt = 0; nt < 8; ++nt) {
                float v = acc[mt][nt][r] + bias;
                orow[nt * 16] = v;
                ps += v; ps2 += v * v;
            }
            #pragma unroll
            for (int m = 8; m; m >>= 1) {
                ps  += __shfl_xor(ps,  m, 16);
                ps2 += __shfl_xor(ps2, m, 16);
            }
            if (lc == 0) {
                atomicAdd(&statS[g * COUT_G + ocg],  (double)ps);
                atomicAdd(&statS2[g * COUT_G + ocg], (double)ps2);
            }
        }
    }
}

// ---------------- K2: finalize BN scale/shift ----------------
__global__ __launch_bounds__(256) void finalize_k(
    const double* __restrict__ statS, const double* __restrict__ statS2,
    const float* __restrict__ gamma, const float* __restrict__ beta,
    float* __restrict__ scaleC, float* __restrict__ shiftC) {
    int c = blockIdx.x * 256 + threadIdx.x;
    if (c >= COUT) return;
    double N = (double)Bn * Ss;
    double mean = statS[c] / N;
    double var  = statS2[c] / N - mean * mean;
    float sc = gamma[c] * rsqrtf((float)(var + 1e-5));
    scaleC[c] = sc;
    shiftC[c] = beta[c] - (float)mean * sc;
}

// ---------------- K3: zero attn region ----------------
__global__ __launch_bounds__(256) void zerof_k(float* __restrict__ p, int n) {
    int i = blockIdx.x * 256 + threadIdx.x;
    if (i < n) p[i] = 0.f;
}

// ---------------- K4 v3: BN+ReLU fused grouped 1x1, scalar (R4 skeleton) ----
// grid (b*10+g, s-quarter). 256 thr; thread owns one s column.
// Acts staged in LDS (fixes R4's t[64] scratch spill); 8-row blocking,
// block-uniform weight addresses -> SGPR loads.
__global__ __launch_bounds__(256) void qkv_k(
    const float* __restrict__ conv, const float* __restrict__ wqkv,
    const float* __restrict__ scaleC, const float* __restrict__ shiftC,
    const int* __restrict__ y,
    float* __restrict__ q, float* __restrict__ ksub, float* __restrict__ vsub) {
    __shared__ float actl[64][256];   // 64 KB

    int bg = blockIdx.x;
    int b = bg / 10, g = bg % 10;
    int tid = threadIdx.x;
    int s = blockIdx.y * 256 + tid;
    int yv = __builtin_amdgcn_readfirstlane(y[b]);

    // ---- stage act = relu(bn(conv)) for this s-quarter ----
    const float* cb = conv + ((size_t)b * COUT + g * COUT_G) * Ss + blockIdx.y * 256;
    for (int e = tid; e < 64 * 256; e += 256) {
        int c = e >> 8, sp = e & 255;
        float v = cb[(size_t)c * Ss + sp];
        actl[c][sp] = fmaxf(fmaf(v, scaleC[g * COUT_G + c], shiftC[g * COUT_G + c]), 0.f);
    }
    __syncthreads();

    // ---- q rows in this group ----
    int q0 = g * 192;
    int q1 = q0 + 192 < COUT ? q0 + 192 : COUT;
    for (int r0 = q0; r0 < q1; r0 += 8) {
        const float* wr = wqkv + (size_t)r0 * COUT_G;
        float a[8];
        #pragma unroll
        for (int r = 0; r < 8; ++r) a[r] = 0.f;
        for (int c = 0; c < 64; ++c) {
            float tv = actl[c][tid];
            #pragma unroll
            for (int r = 0; r < 8; ++r) a[r] = fmaf(wr[r * 64 + c], tv, a[r]);
        }
        int h = r0 / Dd, d = r0 - h * Dd;   // 8|160: never crosses a head
        float* dq = q + (((size_t)(b * NH + h)) * Dd + d) * Ss + s;
        #pragma unroll
        for (int r = 0; r < 8; ++r) dq[(size_t)r * Ss] = a[r];
    }
    // ---- k rows (16 per head; block fully inside one group) ----
    for (int h = 0; h < NH; ++h) {
        int base = COUT + h * Dd + yv * ALLOCC;
        if (base / 192 != g) continue;
        for (int j0 = 0; j0 < 16; j0 += 8) {
            const float* wr = wqkv + (size_t)(base + j0) * COUT_G;
            float a[8];
            #pragma unroll
            for (int r = 0; r < 8; ++r) a[r] = 0.f;
            for (int c = 0; c < 64; ++c) {
                float tv = actl[c][tid];
                #pragma unroll
                for (int r = 0; r < 8; ++r) a[r] = fmaf(wr[r * 64 + c], tv, a[r]);
            }
            float* dk = ksub + (((size_t)(b * NH + h)) * ALLOCC + j0) * Ss + s;
            #pragma unroll
            for (int r = 0; r < 8; ++r) dk[(size_t)r * Ss] = a[r];
        }
    }
    // ---- v rows ----
    for (int h = 0; h < NH; ++h) {
        int base = 2 * COUT + h * Dd + yv * ALLOCC;
        if (base / 192 != g) continue;
        for (int j0 = 0; j0 < 16; j0 += 8) {
            const float* wr = wqkv + (size_t)(base + j0) * COUT_G;
            float a[8];
            #pragma unroll
            for (int r = 0; r < 8; ++r) a[r] = 0.f;
            for (int c = 0; c < 64; ++c) {
                float tv = actl[c][tid];
                #pragma unroll
                for (int r = 0; r < 8; ++r) a[r] = fmaf(wr[r * 64 + c], tv, a[r]);
            }
            float* dv = vsub + (((size_t)(b * NH + h)) * ALLOCC + j0) * Ss + s;
            #pragma unroll
            for (int r = 0; r < 8; ++r) dv[(size_t)r * Ss] = a[r];
        }
    }
}

// ---------------- K5: attention per (b,h) block (R4-proven fp32) ------------
__global__ __launch_bounds__(256) void attn_k(
    const float* __restrict__ q, const float* __restrict__ ksub,
    const float* __restrict__ vsub, const int* __restrict__ y,
    float* __restrict__ o, float* __restrict__ attn) {
    __shared__ float qv[160 * 68];
    __shared__ float klds[16 * 68];
    __shared__ float plds[160 * 16];

    int bh = blockIdx.x;
    int b = bh >> 2, h = bh & 3;
    int tid = threadIdx.x;
    int jt = tid & 15;
    int ig = tid >> 4;

    const float* qb = q    + (size_t)bh * Dd * Ss;
    const float* kb = ksub + (size_t)bh * ALLOCC * Ss;
    const float* vb = vsub + (size_t)bh * ALLOCC * Ss;

    float acc[10];
    #pragma unroll
    for (int r = 0; r < 10; ++r) acc[r] = 0.f;

    for (int s0 = 0; s0 < Ss; s0 += 64) {
        for (int e = tid; e < 160 * 64; e += 256) {
            int i = e >> 6, s = e & 63;
            qv[i * 68 + s] = qb[(size_t)i * Ss + s0 + s];
        }
        for (int e = tid; e < 16 * 64; e += 256) {
            int j = e >> 6, s = e & 63;
            klds[j * 68 + s] = kb[(size_t)j * Ss + s0 + s];
        }
        __syncthreads();
        for (int s = 0; s < 64; s += 4) {
            float4 kq = *(const float4*)&klds[jt * 68 + s];
            #pragma unroll
            for (int r = 0; r < 10; ++r) {
                int i = ig + 16 * r;
                float4 qq = *(const float4*)&qv[i * 68 + s];
                acc[r] += qq.x * kq.x + qq.y * kq.y + qq.z * kq.z + qq.w * kq.w;
            }
        }
        __syncthreads();
    }

    int ycol = y[b] * ALLOCC;
    #pragma unroll
    for (int r = 0; r < 10; ++r) {
        float d = acc[r] * ATT_SCALE;
        float mx = d;
        for (int m = 8; m; m >>= 1) mx = fmaxf(mx, __shfl_xor(mx, m, 16));
        float e = __expf(d - mx);
        float sum = e;
        for (int m = 8; m; m >>= 1) sum += __shfl_xor(sum, m, 16);
        float p = e / sum;
        int i = ig + 16 * r;
        plds[i * 16 + jt] = p;
        attn[((size_t)bh * Dd + i) * Dd + ycol + jt] = p;
    }
    __syncthreads();

    float* vlds = qv;
    for (int s0 = 0; s0 < Ss; s0 += 256) {
        for (int e = tid; e < 16 * 256; e += 256) {
            int j = e >> 8, s = e & 255;
            vlds[j * 256 + s] = vb[(size_t)j * Ss + s0 + s];
        }
        __syncthreads();
        float vr[16];
        #pragma unroll
        for (int j = 0; j < 16; ++j) vr[j] = vlds[j * 256 + tid];
        float* obp = o + ((size_t)b * COUT + h * Dd) * Ss + s0 + tid;
        for (int i = 0; i < Dd; ++i) {
            const float4* p4 = (const float4*)&plds[i * 16];
            float a = 0.f;
            #pragma unroll
            for (int j4 = 0; j4 < 4; ++j4) {
                float4 pv = p4[j4];
                a += pv.x * vr[j4 * 4 + 0] + pv.y * vr[j4 * 4 + 1]
                   + pv.z * vr[j4 * 4 + 2] + pv.w * vr[j4 * 4 + 3];
            }
            obp[(size_t)i * Ss] = a;
        }
        __syncthreads();
    }
}

extern "C" void kernel_launch(void* const* d_in, const int* in_sizes, int n_in,
                              void* d_out, int out_size, void* d_ws, size_t ws_size,
                              hipStream_t stream) {
    const float* x     = (const float*)d_in[0];
    const int*   y     = (const int*)  d_in[1];
    const float* w1    = (const float*)d_in[2];
    const float* b1    = (const float*)d_in[3];
    const float* gamma = (const float*)d_in[4];
    const float* beta  = (const float*)d_in[5];
    const float* wqkv  = (const float*)d_in[6];

    float* o    = (float*)d_out;
    float* attn = o + (size_t)Bn * COUT * Ss;

    float* ws     = (float*)d_ws;
    float* conv   = ws;
    float* qf     = conv + (size_t)Bn * COUT * Ss;
    float* kf     = qf   + (size_t)Bn * NH * Dd * Ss;
    float* vf     = kf   + (size_t)Bn * NH * ALLOCC * Ss;
    float* scaleC = vf   + (size_t)Bn * NH * ALLOCC * Ss;
    float* shiftC = scaleC + COUT;
    double* statS  = (double*)(shiftC + COUT);
    double* statS2 = statS + COUT;

    hipMemsetAsync(statS, 0, 2 * COUT * sizeof(double), stream);
    conv_mfma_k<<<Bn * 10, 512, 0, stream>>>(x, w1, b1, conv, statS, statS2);
    finalize_k<<<(COUT + 255) / 256, 256, 0, stream>>>(statS, statS2, gamma, beta, scaleC, shiftC);
    zerof_k<<<(Bn * NH * Dd * Dd + 255) / 256, 256, 0, stream>>>(attn, Bn * NH * Dd * Dd);
    qkv_k<<<dim3(Bn * 10, 4), 256, 0, stream>>>(conv, wqkv, scaleC, shiftC, y, qf, kf, vf);
    attn_k<<<Bn * NH, 256, 0, stream>>>(qf, kf, vf, y, o, attn);
}

// Round 10
// 542.229 us; speedup vs baseline: 1.2846x; 1.2846x over previous
//
#include <hip/hip_runtime.h>
#include <math.h>

namespace {
constexpr int Bn    = 64;
constexpr int CIN   = 320;
constexpr int COUT  = 640;
constexpr int CIN_G = 32;   // 320/10
constexpr int COUT_G= 64;   // 640/10
constexpr int NH    = 4;
constexpr int Dd    = 160;
constexpr int ALLOCC= 16;
constexpr int Ss    = 1024; // 32*32
constexpr float ATT_SCALE = 0.0395284707521047f; // 640^-0.5

typedef float  f32x4  __attribute__((ext_vector_type(4)));
typedef int    i32x4  __attribute__((ext_vector_type(4)));

__device__ inline unsigned bf16rne(float f) {
    unsigned u = __float_as_uint(f);
    return (u + 0x7FFFu + ((u >> 16) & 1u)) >> 16;
}
__device__ inline unsigned packbf16(float a, float b) {
    return bf16rne(a) | (bf16rne(b) << 16);
}
}

// ---------------- K1: grouped conv3x3 via MFMA implicit GEMM (R4 asm, proven)
__global__ __launch_bounds__(512, 2) void conv_mfma_k(
    const float* __restrict__ x, const float* __restrict__ w1,
    const float* __restrict__ b1, float* __restrict__ out,
    double* __restrict__ statS, double* __restrict__ statS2) {
    __shared__ __align__(16) unsigned short xl[34 * 34 * 32];
    __shared__ __align__(16) unsigned short wl[9 * 64 * 32];

    int bg = blockIdx.x;
    int b = bg / 10, g = bg % 10;
    int tid = threadIdx.x;
    int wid = tid >> 6;
    int lane = tid & 63;
    int lc = lane & 15;
    int kl = (lane >> 4) * 8;

    unsigned* xl32 = (unsigned*)xl;
    unsigned* wl32 = (unsigned*)wl;

    for (int e = tid; e < 34 * 34 * 32 / 8; e += 512)
        *(i32x4*)&xl[e * 8] = i32x4{0, 0, 0, 0};
    __syncthreads();

    const float* xg = x + ((size_t)b * CIN + g * CIN_G) * Ss;
    for (int e = tid; e < 16 * Ss; e += 512) {
        int icp = e & 15, sp = e >> 4;
        int r = (sp >> 5) + 1, c = (sp & 31) + 1;
        float f0 = xg[(size_t)(2 * icp) * Ss + sp];
        float f1 = xg[(size_t)(2 * icp + 1) * Ss + sp];
        xl32[(r * 34 + c) * 16 + icp] = packbf16(f0, f1);
    }
    const float* wg = w1 + (size_t)(g * COUT_G) * (CIN_G * 9);
    for (int e = tid; e < 9 * 64 * 16; e += 512) {
        int icp = e & 15, oc = (e >> 4) & 63, dyx = e >> 10;
        float f0 = wg[oc * 288 + (2 * icp) * 9 + dyx];
        float f1 = wg[oc * 288 + (2 * icp + 1) * 9 + dyx];
        wl32[(dyx * 64 + oc) * 16 + icp] = packbf16(f0, f1);
    }
    __syncthreads();

    f32x4 acc[4][8];
    #pragma unroll
    for (int mt = 0; mt < 4; ++mt)
        #pragma unroll
        for (int nt = 0; nt < 8; ++nt) acc[mt][nt] = f32x4{0.f, 0.f, 0.f, 0.f};

    for (int dyx = 0; dyx < 9; ++dyx) {
        int dy = dyx / 3, dx = dyx % 3;
        const unsigned short* wbase = wl + dyx * 2048 + lc * 32 + kl;
        i32x4 af[4];
        #pragma unroll
        for (int mt = 0; mt < 4; ++mt)
            af[mt] = *(const i32x4*)(wbase + mt * 512);

        const unsigned short* xbase = xl + (dy * 34 + dx + lc) * 32 + kl
                                         + wid * 4 * 1088;
        #pragma unroll
        for (int nt = 0; nt < 8; ++nt) {
            i32x4 bf = *(const i32x4*)(xbase + (nt >> 1) * 1088 + (nt & 1) * 512);
            #pragma unroll
            for (int mt = 0; mt < 4; ++mt)
                asm("v_mfma_f32_16x16x32_bf16 %0, %1, %2, %0"
                    : "+v"(acc[mt][nt]) : "v"(af[mt]), "v"(bf));
        }
    }

    #pragma unroll
    for (int mt = 0; mt < 4; ++mt) {
        #pragma unroll
        for (int r = 0; r < 4; ++r) {
            int ocg = mt * 16 + (lane >> 4) * 4 + r;
            float bias = b1[g * COUT_G + ocg];
            float ps = 0.f, ps2 = 0.f;
            float* orow = out + ((size_t)b * COUT + g * COUT_G + ocg) * Ss
                              + wid * 128 + lc;
            #pragma unroll
            for (int nt = 0; nt < 8; ++nt) {
                float v = acc[mt][nt][r] + bias;
                orow[nt * 16] = v;
                ps += v; ps2 += v * v;
            }
            #pragma unroll
            for (int m = 8; m; m >>= 1) {
                ps  += __shfl_xor(ps,  m, 16);
                ps2 += __shfl_xor(ps2, m, 16);
            }
            if (lc == 0) {
                atomicAdd(&statS[g * COUT_G + ocg],  (double)ps);
                atomicAdd(&statS2[g * COUT_G + ocg], (double)ps2);
            }
        }
    }
}

// ---------------- K2: finalize BN scale/shift ----------------
__global__ __launch_bounds__(256) void finalize_k(
    const double* __restrict__ statS, const double* __restrict__ statS2,
    const float* __restrict__ gamma, const float* __restrict__ beta,
    float* __restrict__ scaleC, float* __restrict__ shiftC) {
    int c = blockIdx.x * 256 + threadIdx.x;
    if (c >= COUT) return;
    double N = (double)Bn * Ss;
    double mean = statS[c] / N;
    double var  = statS2[c] / N - mean * mean;
    float sc = gamma[c] * rsqrtf((float)(var + 1e-5));
    scaleC[c] = sc;
    shiftC[c] = beta[c] - (float)mean * sc;
}

// ---------------- K3: zero attn region ----------------
__global__ __launch_bounds__(256) void zerof_k(float* __restrict__ p, int n) {
    int i = blockIdx.x * 256 + threadIdx.x;
    if (i < n) p[i] = 0.f;
}

// ---------------- K4 v4: BN+ReLU fused grouped 1x1, float4-ILP scalar -------
// grid (b*10+g, s-quarter). 256 thr; thread owns one s column.
// act in LDS as float4[16 cg][256 s] (4-channel interleave); per row-group:
// 16 ds_read_b128 + 512 straight-line FMAs (SGPR weights) — ILP hides latency.
__global__ __launch_bounds__(256) void qkv_k(
    const float* __restrict__ conv, const float* __restrict__ wqkv,
    const float* __restrict__ scaleC, const float* __restrict__ shiftC,
    const int* __restrict__ y,
    float* __restrict__ q, float* __restrict__ ksub, float* __restrict__ vsub) {
    __shared__ __align__(16) float4 actI[16][256];   // 64 KB

    int bg = blockIdx.x;
    int b = bg / 10, g = bg % 10;
    int tid = threadIdx.x;
    int s = blockIdx.y * 256 + tid;
    int yv = __builtin_amdgcn_readfirstlane(y[b]);

    // ---- stage act = relu(bn(conv)), 4-channel interleave ----
    const float* cb = conv + ((size_t)b * COUT + g * COUT_G) * Ss + blockIdx.y * 256;
    #pragma unroll
    for (int cg = 0; cg < 16; ++cg) {
        int c0 = cg * 4;
        float4 v;
        v.x = fmaxf(fmaf(cb[(size_t)(c0 + 0) * Ss + tid], scaleC[g * 64 + c0 + 0], shiftC[g * 64 + c0 + 0]), 0.f);
        v.y = fmaxf(fmaf(cb[(size_t)(c0 + 1) * Ss + tid], scaleC[g * 64 + c0 + 1], shiftC[g * 64 + c0 + 1]), 0.f);
        v.z = fmaxf(fmaf(cb[(size_t)(c0 + 2) * Ss + tid], scaleC[g * 64 + c0 + 2], shiftC[g * 64 + c0 + 2]), 0.f);
        v.w = fmaxf(fmaf(cb[(size_t)(c0 + 3) * Ss + tid], scaleC[g * 64 + c0 + 3], shiftC[g * 64 + c0 + 3]), 0.f);
        actI[cg][tid] = v;
    }
    __syncthreads();

    // ---- 8-row blocks: q rows of this group, then k/v rows if in group ----
    #define DO8(R0, DST)                                                     \
    {                                                                        \
        const float* wr = wqkv + (size_t)(R0) * COUT_G;                      \
        float a[8];                                                          \
        _Pragma("unroll")                                                    \
        for (int r = 0; r < 8; ++r) a[r] = 0.f;                             \
        _Pragma("unroll")                                                    \
        for (int cg = 0; cg < 16; ++cg) {                                    \
            float4 av = actI[cg][tid];                                       \
            _Pragma("unroll")                                                \
            for (int r = 0; r < 8; ++r) {                                    \
                a[r] = fmaf(wr[r * 64 + cg * 4 + 0], av.x, a[r]);            \
                a[r] = fmaf(wr[r * 64 + cg * 4 + 1], av.y, a[r]);            \
                a[r] = fmaf(wr[r * 64 + cg * 4 + 2], av.z, a[r]);            \
                a[r] = fmaf(wr[r * 64 + cg * 4 + 3], av.w, a[r]);            \
            }                                                                \
        }                                                                    \
        _Pragma("unroll")                                                    \
        for (int r = 0; r < 8; ++r) (DST)[(size_t)r * Ss] = a[r];            \
    }

    int q0 = g * 192;
    int q1 = q0 + 192 < COUT ? q0 + 192 : COUT;
    for (int r0 = q0; r0 < q1; r0 += 8) {
        int h = r0 / Dd, d = r0 - h * Dd;   // 8|160: never crosses a head
        float* dq = q + (((size_t)(b * NH + h)) * Dd + d) * Ss + s;
        DO8(r0, dq)
    }
    for (int h = 0; h < NH; ++h) {
        int base = COUT + h * Dd + yv * ALLOCC;
        if (base / 192 != g) continue;
        for (int j0 = 0; j0 < 16; j0 += 8) {
            float* dk = ksub + (((size_t)(b * NH + h)) * ALLOCC + j0) * Ss + s;
            DO8(base + j0, dk)
        }
    }
    for (int h = 0; h < NH; ++h) {
        int base = 2 * COUT + h * Dd + yv * ALLOCC;
        if (base / 192 != g) continue;
        for (int j0 = 0; j0 < 16; j0 += 8) {
            float* dv = vsub + (((size_t)(b * NH + h)) * ALLOCC + j0) * Ss + s;
            DO8(base + j0, dv)
        }
    }
    #undef DO8
}

// ---------------- K5a: QK^T partials (grid bh x 4 s-quarters) ---------------
__global__ __launch_bounds__(256) void qk_k(
    const float* __restrict__ q, const float* __restrict__ ksub,
    float* __restrict__ partial) {
    __shared__ float qv[160 * 68];
    __shared__ float klds[16 * 68];

    int bh = blockIdx.x, sq = blockIdx.y;
    int tid = threadIdx.x;
    int jt = tid & 15;
    int ig = tid >> 4;

    const float* qb = q    + (size_t)bh * Dd * Ss     + sq * 256;
    const float* kb = ksub + (size_t)bh * ALLOCC * Ss + sq * 256;

    float acc[10];
    #pragma unroll
    for (int r = 0; r < 10; ++r) acc[r] = 0.f;

    for (int s0 = 0; s0 < 256; s0 += 64) {
        for (int e = tid; e < 160 * 64; e += 256) {
            int i = e >> 6, s2 = e & 63;
            qv[i * 68 + s2] = qb[(size_t)i * Ss + s0 + s2];
        }
        for (int e = tid; e < 16 * 64; e += 256) {
            int j = e >> 6, s2 = e & 63;
            klds[j * 68 + s2] = kb[(size_t)j * Ss + s0 + s2];
        }
        __syncthreads();
        for (int s2 = 0; s2 < 64; s2 += 4) {
            float4 kq = *(const float4*)&klds[jt * 68 + s2];
            #pragma unroll
            for (int r = 0; r < 10; ++r) {
                int i = ig + 16 * r;
                float4 qq = *(const float4*)&qv[i * 68 + s2];
                acc[r] += qq.x * kq.x + qq.y * kq.y + qq.z * kq.z + qq.w * kq.w;
            }
        }
        __syncthreads();
    }
    float* pp = partial + ((size_t)(bh * 4 + sq)) * (Dd * 16);
    #pragma unroll
    for (int r = 0; r < 10; ++r)
        pp[(ig + 16 * r) * 16 + jt] = acc[r];
}

// ---------------- K5b: reduce + masked softmax -> attn, P -------------------
__global__ __launch_bounds__(256) void sm_k(
    const float* __restrict__ partial, const int* __restrict__ y,
    float* __restrict__ attn, float* __restrict__ P) {
    int bh = blockIdx.x;
    int b = bh >> 2;
    int tid = threadIdx.x;
    int jt = tid & 15;
    int ig = tid >> 4;
    int ycol = y[b] * ALLOCC;

    const float* pb = partial + (size_t)bh * 4 * (Dd * 16);
    #pragma unroll
    for (int r = 0; r < 10; ++r) {
        int i = ig + 16 * r;
        const float* pp = pb + i * 16 + jt;
        float d = (pp[0] + pp[Dd * 16] + pp[2 * Dd * 16] + pp[3 * Dd * 16]) * ATT_SCALE;
        float mx = d;
        #pragma unroll
        for (int m = 8; m; m >>= 1) mx = fmaxf(mx, __shfl_xor(mx, m, 16));
        float e = __expf(d - mx);
        float sum = e;
        #pragma unroll
        for (int m = 8; m; m >>= 1) sum += __shfl_xor(sum, m, 16);
        float p = e / sum;
        attn[((size_t)bh * Dd + i) * Dd + ycol + jt] = p;
        P[(size_t)bh * (Dd * 16) + i * 16 + jt] = p;
    }
}

// ---------------- K5c: PV (grid bh x 4 s-quarters) --------------------------
__global__ __launch_bounds__(256) void pv_k(
    const float* __restrict__ P, const float* __restrict__ vsub,
    float* __restrict__ o) {
    __shared__ float plds[160 * 16];
    __shared__ float vlds[16][256];

    int bh = blockIdx.x, sq = blockIdx.y;
    int b = bh >> 2, h = bh & 3;
    int tid = threadIdx.x;

    for (int e = tid; e < 160 * 16; e += 256)
        plds[e] = P[(size_t)bh * (Dd * 16) + e];
    #pragma unroll
    for (int j = 0; j < 16; ++j)
        vlds[j][tid] = vsub[((size_t)bh * ALLOCC + j) * Ss + sq * 256 + tid];
    __syncthreads();

    float vr[16];
    #pragma unroll
    for (int j = 0; j < 16; ++j) vr[j] = vlds[j][tid];

    float* obp = o + ((size_t)b * COUT + h * Dd) * Ss + sq * 256 + tid;
    for (int i = 0; i < Dd; ++i) {
        const float4* p4 = (const float4*)&plds[i * 16];
        float a = 0.f;
        #pragma unroll
        for (int j4 = 0; j4 < 4; ++j4) {
            float4 pv = p4[j4];
            a += pv.x * vr[j4 * 4 + 0] + pv.y * vr[j4 * 4 + 1]
               + pv.z * vr[j4 * 4 + 2] + pv.w * vr[j4 * 4 + 3];
        }
        obp[(size_t)i * Ss] = a;
    }
}

extern "C" void kernel_launch(void* const* d_in, const int* in_sizes, int n_in,
                              void* d_out, int out_size, void* d_ws, size_t ws_size,
                              hipStream_t stream) {
    const float* x     = (const float*)d_in[0];
    const int*   y     = (const int*)  d_in[1];
    const float* w1    = (const float*)d_in[2];
    const float* b1    = (const float*)d_in[3];
    const float* gamma = (const float*)d_in[4];
    const float* beta  = (const float*)d_in[5];
    const float* wqkv  = (const float*)d_in[6];

    float* o    = (float*)d_out;
    float* attn = o + (size_t)Bn * COUT * Ss;

    float* ws     = (float*)d_ws;
    float* conv   = ws;
    float* qf     = conv + (size_t)Bn * COUT * Ss;
    float* kf     = qf   + (size_t)Bn * NH * Dd * Ss;
    float* vf     = kf   + (size_t)Bn * NH * ALLOCC * Ss;
    float* part   = vf   + (size_t)Bn * NH * ALLOCC * Ss;       // 256*4*2560 f
    float* Pbuf   = part + (size_t)Bn * NH * 4 * Dd * ALLOCC;   // 256*2560 f
    float* scaleC = Pbuf + (size_t)Bn * NH * Dd * ALLOCC;
    float* shiftC = scaleC + COUT;
    double* statS  = (double*)(shiftC + COUT);
    double* statS2 = statS + COUT;

    hipMemsetAsync(statS, 0, 2 * COUT * sizeof(double), stream);
    conv_mfma_k<<<Bn * 10, 512, 0, stream>>>(x, w1, b1, conv, statS, statS2);
    finalize_k<<<(COUT + 255) / 256, 256, 0, stream>>>(statS, statS2, gamma, beta, scaleC, shiftC);
    zerof_k<<<(Bn * NH * Dd * Dd + 255) / 256, 256, 0, stream>>>(attn, Bn * NH * Dd * Dd);
    qkv_k<<<dim3(Bn * 10, 4), 256, 0, stream>>>(conv, wqkv, scaleC, shiftC, y, qf, kf, vf);
    qk_k<<<dim3(Bn * NH, 4), 256, 0, stream>>>(qf, kf, part);
    sm_k<<<Bn * NH, 256, 0, stream>>>(part, y, attn, Pbuf);
    pv_k<<<dim3(Bn * NH, 4), 256, 0, stream>>>(Pbuf, vf, o);
}

// Round 11
// 488.292 us; speedup vs baseline: 1.4265x; 1.1105x over previous
//
#include <hip/hip_runtime.h>
#include <math.h>

namespace {
constexpr int Bn    = 64;
constexpr int CIN   = 320;
constexpr int COUT  = 640;
constexpr int CIN_G = 32;   // 320/10
constexpr int COUT_G= 64;   // 640/10
constexpr int NH    = 4;
constexpr int Dd    = 160;
constexpr int ALLOCC= 16;
constexpr int Ss    = 1024; // 32*32
constexpr float ATT_SCALE = 0.0395284707521047f; // 640^-0.5

typedef float  f32x4  __attribute__((ext_vector_type(4)));
typedef int    i32x4  __attribute__((ext_vector_type(4)));

__device__ inline unsigned bf16rne(float f) {
    unsigned u = __float_as_uint(f);
    return (u + 0x7FFFu + ((u >> 16) & 1u)) >> 16;
}
__device__ inline unsigned packbf16(float a, float b) {
    return bf16rne(a) | (bf16rne(b) << 16);
}
}

// ---------------- K1: grouped conv3x3 via MFMA implicit GEMM (R4 asm, proven)
__global__ __launch_bounds__(512, 2) void conv_mfma_k(
    const float* __restrict__ x, const float* __restrict__ w1,
    const float* __restrict__ b1, float* __restrict__ out,
    double* __restrict__ statS, double* __restrict__ statS2) {
    __shared__ __align__(16) unsigned short xl[34 * 34 * 32];
    __shared__ __align__(16) unsigned short wl[9 * 64 * 32];

    int bg = blockIdx.x;
    int b = bg / 10, g = bg % 10;
    int tid = threadIdx.x;
    int wid = tid >> 6;
    int lane = tid & 63;
    int lc = lane & 15;
    int kl = (lane >> 4) * 8;

    unsigned* xl32 = (unsigned*)xl;
    unsigned* wl32 = (unsigned*)wl;

    for (int e = tid; e < 34 * 34 * 32 / 8; e += 512)
        *(i32x4*)&xl[e * 8] = i32x4{0, 0, 0, 0};
    __syncthreads();

    const float* xg = x + ((size_t)b * CIN + g * CIN_G) * Ss;
    for (int e = tid; e < 16 * Ss; e += 512) {
        int icp = e & 15, sp = e >> 4;
        int r = (sp >> 5) + 1, c = (sp & 31) + 1;
        float f0 = xg[(size_t)(2 * icp) * Ss + sp];
        float f1 = xg[(size_t)(2 * icp + 1) * Ss + sp];
        xl32[(r * 34 + c) * 16 + icp] = packbf16(f0, f1);
    }
    const float* wg = w1 + (size_t)(g * COUT_G) * (CIN_G * 9);
    for (int e = tid; e < 9 * 64 * 16; e += 512) {
        int icp = e & 15, oc = (e >> 4) & 63, dyx = e >> 10;
        float f0 = wg[oc * 288 + (2 * icp) * 9 + dyx];
        float f1 = wg[oc * 288 + (2 * icp + 1) * 9 + dyx];
        wl32[(dyx * 64 + oc) * 16 + icp] = packbf16(f0, f1);
    }
    __syncthreads();

    f32x4 acc[4][8];
    #pragma unroll
    for (int mt = 0; mt < 4; ++mt)
        #pragma unroll
        for (int nt = 0; nt < 8; ++nt) acc[mt][nt] = f32x4{0.f, 0.f, 0.f, 0.f};

    for (int dyx = 0; dyx < 9; ++dyx) {
        int dy = dyx / 3, dx = dyx % 3;
        const unsigned short* wbase = wl + dyx * 2048 + lc * 32 + kl;
        i32x4 af[4];
        #pragma unroll
        for (int mt = 0; mt < 4; ++mt)
            af[mt] = *(const i32x4*)(wbase + mt * 512);

        const unsigned short* xbase = xl + (dy * 34 + dx + lc) * 32 + kl
                                         + wid * 4 * 1088;
        #pragma unroll
        for (int nt = 0; nt < 8; ++nt) {
            i32x4 bf = *(const i32x4*)(xbase + (nt >> 1) * 1088 + (nt & 1) * 512);
            #pragma unroll
            for (int mt = 0; mt < 4; ++mt)
                asm("v_mfma_f32_16x16x32_bf16 %0, %1, %2, %0"
                    : "+v"(acc[mt][nt]) : "v"(af[mt]), "v"(bf));
        }
    }

    #pragma unroll
    for (int mt = 0; mt < 4; ++mt) {
        #pragma unroll
        for (int r = 0; r < 4; ++r) {
            int ocg = mt * 16 + (lane >> 4) * 4 + r;
            float bias = b1[g * COUT_G + ocg];
            float ps = 0.f, ps2 = 0.f;
            float* orow = out + ((size_t)b * COUT + g * COUT_G + ocg) * Ss
                              + wid * 128 + lc;
            #pragma unroll
            for (int nt = 0; nt < 8; ++nt) {
                float v = acc[mt][nt][r] + bias;
                orow[nt * 16] = v;
                ps += v; ps2 += v * v;
            }
            #pragma unroll
            for (int m = 8; m; m >>= 1) {
                ps  += __shfl_xor(ps,  m, 16);
                ps2 += __shfl_xor(ps2, m, 16);
            }
            if (lc == 0) {
                atomicAdd(&statS[g * COUT_G + ocg],  (double)ps);
                atomicAdd(&statS2[g * COUT_G + ocg], (double)ps2);
            }
        }
    }
}

// ---------------- K2: finalize BN scale/shift ----------------
__global__ __launch_bounds__(256) void finalize_k(
    const double* __restrict__ statS, const double* __restrict__ statS2,
    const float* __restrict__ gamma, const float* __restrict__ beta,
    float* __restrict__ scaleC, float* __restrict__ shiftC) {
    int c = blockIdx.x * 256 + threadIdx.x;
    if (c >= COUT) return;
    double N = (double)Bn * Ss;
    double mean = statS[c] / N;
    double var  = statS2[c] / N - mean * mean;
    float sc = gamma[c] * rsqrtf((float)(var + 1e-5));
    scaleC[c] = sc;
    shiftC[c] = beta[c] - (float)mean * sc;
}

// ---------------- K3: zero attn region ----------------
__global__ __launch_bounds__(256) void zerof_k(float* __restrict__ p, int n) {
    int i = blockIdx.x * 256 + threadIdx.x;
    if (i < n) p[i] = 0.f;
}

// ---------------- K4 v5: BN+ReLU fused grouped 1x1, 1024-thread TLP ---------
// grid (b*10+g, s-quarter), block 1024 = 16 waves (8/SIMD at 2 blocks/CU).
// tid&255 = s column, tid>>8 = row-quarter; row-groups dealt round-robin.
__global__ __launch_bounds__(1024) void qkv_k(
    const float* __restrict__ conv, const float* __restrict__ wqkv,
    const float* __restrict__ scaleC, const float* __restrict__ shiftC,
    const int* __restrict__ y,
    float* __restrict__ q, float* __restrict__ ksub, float* __restrict__ vsub) {
    __shared__ __align__(16) float4 actI[16][256];   // 64 KB

    int bg = blockIdx.x;
    int b = bg / 10, g = bg % 10;
    int tid = threadIdx.x;
    int sc_ = tid & 255;
    int qt  = tid >> 8;          // 0..3
    int s = blockIdx.y * 256 + sc_;
    int yv = __builtin_amdgcn_readfirstlane(y[b]);

    // ---- stage act = relu(bn(conv)), 4-channel interleave ----
    const float* cb = conv + ((size_t)b * COUT + g * COUT_G) * Ss + blockIdx.y * 256;
    for (int e = tid; e < 16 * 256; e += 1024) {
        int cg = e >> 8, sp = e & 255;
        int c0 = cg * 4;
        float4 v;
        v.x = fmaxf(fmaf(cb[(size_t)(c0 + 0) * Ss + sp], scaleC[g * 64 + c0 + 0], shiftC[g * 64 + c0 + 0]), 0.f);
        v.y = fmaxf(fmaf(cb[(size_t)(c0 + 1) * Ss + sp], scaleC[g * 64 + c0 + 1], shiftC[g * 64 + c0 + 1]), 0.f);
        v.z = fmaxf(fmaf(cb[(size_t)(c0 + 2) * Ss + sp], scaleC[g * 64 + c0 + 2], shiftC[g * 64 + c0 + 2]), 0.f);
        v.w = fmaxf(fmaf(cb[(size_t)(c0 + 3) * Ss + sp], scaleC[g * 64 + c0 + 3], shiftC[g * 64 + c0 + 3]), 0.f);
        actI[cg][sp] = v;
    }
    __syncthreads();

    #define DO8(R0, DST)                                                     \
    {                                                                        \
        const float* wr = wqkv + (size_t)(R0) * COUT_G;                      \
        float a[8];                                                          \
        _Pragma("unroll")                                                    \
        for (int r = 0; r < 8; ++r) a[r] = 0.f;                             \
        _Pragma("unroll")                                                    \
        for (int cg = 0; cg < 16; ++cg) {                                    \
            float4 av = actI[cg][sc_];                                       \
            _Pragma("unroll")                                                \
            for (int r = 0; r < 8; ++r) {                                    \
                a[r] = fmaf(wr[r * 64 + cg * 4 + 0], av.x, a[r]);            \
                a[r] = fmaf(wr[r * 64 + cg * 4 + 1], av.y, a[r]);            \
                a[r] = fmaf(wr[r * 64 + cg * 4 + 2], av.z, a[r]);            \
                a[r] = fmaf(wr[r * 64 + cg * 4 + 3], av.w, a[r]);            \
            }                                                                \
        }                                                                    \
        _Pragma("unroll")                                                    \
        for (int r = 0; r < 8; ++r) (DST)[(size_t)r * Ss] = a[r];            \
    }

    int idx = 0;
    // ---- q rows of this group ----
    int q0 = g * 192;
    int q1 = q0 + 192 < COUT ? q0 + 192 : COUT;
    for (int r0 = q0; r0 < q1; r0 += 8) {
        if ((idx & 3) == qt) {
            int h = r0 / Dd, d = r0 - h * Dd;   // 8|160: never crosses a head
            float* dq = q + (((size_t)(b * NH + h)) * Dd + d) * Ss + s;
            DO8(r0, dq)
        }
        ++idx;
    }
    // ---- k rows (16 per head; block fully inside one group) ----
    for (int h = 0; h < NH; ++h) {
        int base = COUT + h * Dd + yv * ALLOCC;
        if (base / 192 != g) continue;
        for (int j0 = 0; j0 < 16; j0 += 8) {
            if ((idx & 3) == qt) {
                float* dk = ksub + (((size_t)(b * NH + h)) * ALLOCC + j0) * Ss + s;
                DO8(base + j0, dk)
            }
            ++idx;
        }
    }
    // ---- v rows ----
    for (int h = 0; h < NH; ++h) {
        int base = 2 * COUT + h * Dd + yv * ALLOCC;
        if (base / 192 != g) continue;
        for (int j0 = 0; j0 < 16; j0 += 8) {
            if ((idx & 3) == qt) {
                float* dv = vsub + (((size_t)(b * NH + h)) * ALLOCC + j0) * Ss + s;
                DO8(base + j0, dv)
            }
            ++idx;
        }
    }
    #undef DO8
}

// ---------------- K5a: QK^T partials (grid bh x 4 s-quarters) ---------------
__global__ __launch_bounds__(256) void qk_k(
    const float* __restrict__ q, const float* __restrict__ ksub,
    float* __restrict__ partial) {
    __shared__ float qv[160 * 68];
    __shared__ float klds[16 * 68];

    int bh = blockIdx.x, sq = blockIdx.y;
    int tid = threadIdx.x;
    int jt = tid & 15;
    int ig = tid >> 4;

    const float* qb = q    + (size_t)bh * Dd * Ss     + sq * 256;
    const float* kb = ksub + (size_t)bh * ALLOCC * Ss + sq * 256;

    float acc[10];
    #pragma unroll
    for (int r = 0; r < 10; ++r) acc[r] = 0.f;

    for (int s0 = 0; s0 < 256; s0 += 64) {
        for (int e = tid; e < 160 * 64; e += 256) {
            int i = e >> 6, s2 = e & 63;
            qv[i * 68 + s2] = qb[(size_t)i * Ss + s0 + s2];
        }
        for (int e = tid; e < 16 * 64; e += 256) {
            int j = e >> 6, s2 = e & 63;
            klds[j * 68 + s2] = kb[(size_t)j * Ss + s0 + s2];
        }
        __syncthreads();
        for (int s2 = 0; s2 < 64; s2 += 4) {
            float4 kq = *(const float4*)&klds[jt * 68 + s2];
            #pragma unroll
            for (int r = 0; r < 10; ++r) {
                int i = ig + 16 * r;
                float4 qq = *(const float4*)&qv[i * 68 + s2];
                acc[r] += qq.x * kq.x + qq.y * kq.y + qq.z * kq.z + qq.w * kq.w;
            }
        }
        __syncthreads();
    }
    float* pp = partial + ((size_t)(bh * 4 + sq)) * (Dd * 16);
    #pragma unroll
    for (int r = 0; r < 10; ++r)
        pp[(ig + 16 * r) * 16 + jt] = acc[r];
}

// ---------------- K5b: reduce + masked softmax -> attn, P -------------------
__global__ __launch_bounds__(256) void sm_k(
    const float* __restrict__ partial, const int* __restrict__ y,
    float* __restrict__ attn, float* __restrict__ P) {
    int bh = blockIdx.x;
    int b = bh >> 2;
    int tid = threadIdx.x;
    int jt = tid & 15;
    int ig = tid >> 4;
    int ycol = y[b] * ALLOCC;

    const float* pb = partial + (size_t)bh * 4 * (Dd * 16);
    #pragma unroll
    for (int r = 0; r < 10; ++r) {
        int i = ig + 16 * r;
        const float* pp = pb + i * 16 + jt;
        float d = (pp[0] + pp[Dd * 16] + pp[2 * Dd * 16] + pp[3 * Dd * 16]) * ATT_SCALE;
        float mx = d;
        #pragma unroll
        for (int m = 8; m; m >>= 1) mx = fmaxf(mx, __shfl_xor(mx, m, 16));
        float e = __expf(d - mx);
        float sum = e;
        #pragma unroll
        for (int m = 8; m; m >>= 1) sum += __shfl_xor(sum, m, 16);
        float p = e / sum;
        attn[((size_t)bh * Dd + i) * Dd + ycol + jt] = p;
        P[(size_t)bh * (Dd * 16) + i * 16 + jt] = p;
    }
}

// ---------------- K5c: PV (grid bh x 4 s-quarters) --------------------------
__global__ __launch_bounds__(256) void pv_k(
    const float* __restrict__ P, const float* __restrict__ vsub,
    float* __restrict__ o) {
    __shared__ float plds[160 * 16];
    __shared__ float vlds[16][256];

    int bh = blockIdx.x, sq = blockIdx.y;
    int b = bh >> 2, h = bh & 3;
    int tid = threadIdx.x;

    for (int e = tid; e < 160 * 16; e += 256)
        plds[e] = P[(size_t)bh * (Dd * 16) + e];
    #pragma unroll
    for (int j = 0; j < 16; ++j)
        vlds[j][tid] = vsub[((size_t)bh * ALLOCC + j) * Ss + sq * 256 + tid];
    __syncthreads();

    float vr[16];
    #pragma unroll
    for (int j = 0; j < 16; ++j) vr[j] = vlds[j][tid];

    float* obp = o + ((size_t)b * COUT + h * Dd) * Ss + sq * 256 + tid;
    for (int i = 0; i < Dd; ++i) {
        const float4* p4 = (const float4*)&plds[i * 16];
        float a = 0.f;
        #pragma unroll
        for (int j4 = 0; j4 < 4; ++j4) {
            float4 pv = p4[j4];
            a += pv.x * vr[j4 * 4 + 0] + pv.y * vr[j4 * 4 + 1]
               + pv.z * vr[j4 * 4 + 2] + pv.w * vr[j4 * 4 + 3];
        }
        obp[(size_t)i * Ss] = a;
    }
}

extern "C" void kernel_launch(void* const* d_in, const int* in_sizes, int n_in,
                              void* d_out, int out_size, void* d_ws, size_t ws_size,
                              hipStream_t stream) {
    const float* x     = (const float*)d_in[0];
    const int*   y     = (const int*)  d_in[1];
    const float* w1    = (const float*)d_in[2];
    const float* b1    = (const float*)d_in[3];
    const float* gamma = (const float*)d_in[4];
    const float* beta  = (const float*)d_in[5];
    const float* wqkv  = (const float*)d_in[6];

    float* o    = (float*)d_out;
    float* attn = o + (size_t)Bn * COUT * Ss;

    float* ws     = (float*)d_ws;
    float* conv   = ws;
    float* qf     = conv + (size_t)Bn * COUT * Ss;
    float* kf     = qf   + (size_t)Bn * NH * Dd * Ss;
    float* vf     = kf   + (size_t)Bn * NH * ALLOCC * Ss;
    float* part   = vf   + (size_t)Bn * NH * ALLOCC * Ss;       // 256*4*2560 f
    float* Pbuf   = part + (size_t)Bn * NH * 4 * Dd * ALLOCC;   // 256*2560 f
    float* scaleC = Pbuf + (size_t)Bn * NH * Dd * ALLOCC;
    float* shiftC = scaleC + COUT;
    double* statS  = (double*)(shiftC + COUT);
    double* statS2 = statS + COUT;

    hipMemsetAsync(statS, 0, 2 * COUT * sizeof(double), stream);
    conv_mfma_k<<<Bn * 10, 512, 0, stream>>>(x, w1, b1, conv, statS, statS2);
    finalize_k<<<(COUT + 255) / 256, 256, 0, stream>>>(statS, statS2, gamma, beta, scaleC, shiftC);
    zerof_k<<<(Bn * NH * Dd * Dd + 255) / 256, 256, 0, stream>>>(attn, Bn * NH * Dd * Dd);
    qkv_k<<<dim3(Bn * 10, 4), 1024, 0, stream>>>(conv, wqkv, scaleC, shiftC, y, qf, kf, vf);
    qk_k<<<dim3(Bn * NH, 4), 256, 0, stream>>>(qf, kf, part);
    sm_k<<<Bn * NH, 256, 0, stream>>>(part, y, attn, Pbuf);
    pv_k<<<dim3(Bn * NH, 4), 256, 0, stream>>>(Pbuf, vf, o);
}